// Round 13
// baseline (140.198 us; speedup 1.0000x reference)
//
#include <hip/hip_runtime.h>

// Problem constants
static constexpr int B_ = 64, A_ = 32, BOARD_ = 64, D_ = 5;
static constexpr long long FACN = (long long)B_ * A_ * BOARD_ * BOARD_ * D_; // 41,943,040 floats
static constexpr long long CHN  = (long long)B_ * A_ * BOARD_ * BOARD_;      //  8,388,608 floats
static constexpr int NAG = B_ * A_;                                          // 2048 agents
static constexpr int SL  = BOARD_ * BOARD_ * D_;                             // 20480 floats / agent fac slab
static constexpr int SLC = BOARD_ * BOARD_;                                  //  4096 floats / agent ch slab

// exp(-1/50), exp(-1/20)
static constexpr float FAC_DECAY = 0.9801986733067553f;
static constexpr float INH_DECAY = 0.9512294245007140f;

typedef float f32x4 __attribute__((ext_vector_type(4)));

// Fused kernel. SINGLE-VARIABLE EXPERIMENT vs r12 (best, 137.6 us):
// 256 blocks x 1024 threads (1 block/CU, 16 waves/CU) instead of 512 blocks
// (2 blocks/CU, 32 waves/CU). Tests whether fewer, longer per-CU streams beat
// full occupancy: fill kernels sustain 7 TB/s at ~3 waves/CU, and the
// blocks/CU trend at fixed occupancy was 8->142.5, 2->137.6 us.
// Everything else identical: nt loads + nt stores, software pipeline,
// wave-uniform region pick (group = 4096 vectors), chunk-local corrections.
__global__ __launch_bounds__(1024) void fused_kernel(
    const f32x4* __restrict__ fac4, const f32x4* __restrict__ inh4,
    const f32x4* __restrict__ ch4, f32x4* __restrict__ out4,
    const float* __restrict__ pos, const float* __restrict__ goal,
    const float* __restrict__ spike,
    const float* __restrict__ fac_in, const float* __restrict__ inh_in,
    const float* __restrict__ ch_in,
    const void* __restrict__ coll,
    float* __restrict__ out)
{
    const int FACV = (int)(FACN / 4);       // 10,485,760 vectors (= 2560*4096)
    const int C = 90112;                    // vectors per block (= 22*4096); 256*C = total
    const int t = threadIdx.x;
    const int bid = blockIdx.x;
    const int base = bid * C;

    __shared__ int s_w4, s_h2;
    if (t == 0) { s_w4 = 1; s_h2 = 1; }
    __syncthreads();

    // ---- Phase 1: streaming decay (groups of 4096 vectors) ----
    auto ldgrp = [&](int G, f32x4 v[4], float& c) {
        const f32x4* __restrict__ s;
        if (G < FACV)          { s = fac4 + G;             c = FAC_DECAY; }
        else if (G < 2 * FACV) { s = inh4 + (G - FACV);    c = INH_DECAY; }
        else                   { s = ch4 + (G - 2 * FACV); c = 0.9f; }
        v[0] = __builtin_nontemporal_load(&s[t]);
        v[1] = __builtin_nontemporal_load(&s[t + 1024]);
        v[2] = __builtin_nontemporal_load(&s[t + 2048]);
        v[3] = __builtin_nontemporal_load(&s[t + 3072]);
    };

    {
        f32x4 v[4]; float c;
        ldgrp(base, v, c);
        int off = 0;
        while (true) {
            f32x4 w[4]; float c2;
            const int noff = off + 4096;
            if (noff < C) ldgrp(base + noff, w, c2);   // prefetch next group first
            f32x4* __restrict__ d = out4 + base + off;
            __builtin_nontemporal_store(v[0] * c, &d[t]);
            __builtin_nontemporal_store(v[1] * c, &d[t + 1024]);
            __builtin_nontemporal_store(v[2] * c, &d[t + 2048]);
            __builtin_nontemporal_store(v[3] * c, &d[t + 3072]);
            if (noff >= C) break;
            v[0] = w[0]; v[1] = w[1]; v[2] = w[2]; v[3] = w[3]; c = c2;
            off = noff;
        }
    }

    // ---- collisions-dtype sniff (2048 bytes = smallest possible encoding) ----
    {
        const unsigned int* cw = (const unsigned int*)coll;
        if (t < 512) {
            unsigned int w = cw[t];
            if (!(w == 0u || w == 1u || w == 0x3F800000u)) s_w4 = 0;
            unsigned int lo = w & 0xFFFFu, hi = w >> 16;
            if (!((lo == 0u || lo == 1u || lo == 0x3F80u || lo == 0x3C00u) &&
                  (hi == 0u || hi == 1u || hi == 0x3F80u || hi == 0x3C00u)))
                s_h2 = 0;
        }
    }
    __threadfence_block();
    __syncthreads();   // this block's streaming stores ordered; sniff flags ready
    const int f = s_w4 ? 4 : (s_h2 ? 2 : 1);

    // ---- Phase 2: chunk-local agent corrections ----
    const long long CF = (long long)C * 4;  // 360,448 floats per chunk
    const long long F0 = (long long)bid * CF, F1 = F0 + CF;

    auto fix_agent = [&](int ia, int region) {  // region 0=fac, 1=inh, 2=ch
        float px = pos[ia * 2 + 0];
        float py = pos[ia * 2 + 1];
        int x = min(BOARD_ - 1, max(0, (int)px));   // trunc like .astype(int32); pos >= 0
        int y = min(BOARD_ - 1, max(0, (int)py));
        int lcell = y * BOARD_ + x;                 // 0..4095

        bool c;
        if (f == 4)      c = ((const unsigned int*)coll)[ia] != 0u;
        else if (f == 2) c = ((const unsigned short*)coll)[ia] != 0u;
        else             c = ((const unsigned char*)coll)[ia] != 0u;

        float chv = ch_in[(long long)ia * SLC + lcell] * 0.9f + (c ? 0.1f : 0.0f);
        float safety = 1.0f - fminf(fmaxf(chv, 0.0f), 1.0f);

        if (region == 2) {
            long long fl = 2 * FACN + (long long)ia * SLC + lcell;
            if (fl >= F0 && fl < F1) out[fl] = chv;
            return;
        }

        bool safe = safety > 0.7f;
        float gx = goal[ia * 2 + 0] - px;
        float gy = goal[ia * 2 + 1] - py;
        float n = sqrtf(gx * gx + gy * gy) + 1e-8f;
        float gnx = gx / n, gny = gy / n;
        float align[5];
        align[0] = 0.5f;
        align[1] = (gnx + 1.0f) * 0.5f;
        align[2] = (gny + 1.0f) * 0.5f;
        align[3] = (1.0f - gnx) * 0.5f;
        align[4] = (1.0f - gny) * 0.5f;

        long long cdb = (long long)ia * SL + (long long)lcell * D_;  // within-region float base
#pragma unroll
        for (int d = 0; d < D_; ++d) {
            bool sp = spike[ia * D_ + d] > 0.5f;
            long long fl;
            float v;
            if (region == 0) {
                bool fc = sp && safe && (align[d] > 0.6f);
                v = fac_in[cdb + d] * FAC_DECAY + (fc ? 0.0002f : 0.0f);
                fl = cdb + d;
            } else {
                bool ic = sp && (!safe || (align[d] <= 0.4f));
                v = inh_in[cdb + d] * INH_DECAY + (ic ? 0.0001f : 0.0f);
                fl = FACN + cdb + d;
            }
            if (fl >= F0 && fl < F1) out[fl] = v;
        }
    };

    // fac region: chunk may touch up to ceil(360448/20480)+1 = 19 slabs -> 24 threads
    if (t < 24) {
        long long a1 = min(F1, FACN);
        if (F0 < a1) {
            int ia = (int)(F0 / SL) + t;
            int iaMax = (int)((a1 - 1) / SL);
            if (ia <= iaMax && ia < NAG) fix_agent(ia, 0);
        }
    }
    // inh region: same bound -> 24 threads
    else if (t >= 32 && t < 56) {
        long long b0 = max(F0, FACN), b1 = min(F1, 2 * FACN);
        if (b0 < b1) {
            int ia = (int)((b0 - FACN) / SL) + (t - 32);
            int iaMax = (int)((b1 - FACN - 1) / SL);
            if (ia <= iaMax && ia < NAG) fix_agent(ia, 1);
        }
    }
    // ch region: up to ceil(360448/4096)+1 = 89 slabs -> 96 threads
    else if (t >= 64 && t < 160) {
        long long c0 = max(F0, 2 * FACN), c1 = min(F1, 2 * FACN + CHN);
        if (c0 < c1) {
            int ia = (int)((c0 - 2 * FACN) / SLC) + (t - 64);
            int iaMax = (int)((c1 - 2 * FACN - 1) / SLC);
            if (ia <= iaMax && ia < NAG) fix_agent(ia, 2);
        }
    }
    // safety: 256 blocks x 8 agents = 2048 (floats past all chunks; one writer each)
    else if (t >= 192 && t < 200) {
        int ia = bid * 8 + (t - 192);
        float px = pos[ia * 2 + 0];
        float py = pos[ia * 2 + 1];
        int x = min(BOARD_ - 1, max(0, (int)px));
        int y = min(BOARD_ - 1, max(0, (int)py));
        int lcell = y * BOARD_ + x;
        bool c;
        if (f == 4)      c = ((const unsigned int*)coll)[ia] != 0u;
        else if (f == 2) c = ((const unsigned short*)coll)[ia] != 0u;
        else             c = ((const unsigned char*)coll)[ia] != 0u;
        float chv = ch_in[(long long)ia * SLC + lcell] * 0.9f + (c ? 0.1f : 0.0f);
        out[2 * FACN + CHN + ia] = 1.0f - fminf(fmaxf(chv, 0.0f), 1.0f);
    }
}

extern "C" void kernel_launch(void* const* d_in, const int* in_sizes, int n_in,
                              void* d_out, int out_size, void* d_ws, size_t ws_size,
                              hipStream_t stream) {
    const float* pos   = (const float*)d_in[0];
    const float* goal  = (const float*)d_in[1];
    const float* spike = (const float*)d_in[2];
    const float* fac   = (const float*)d_in[3];
    const float* inh   = (const float*)d_in[4];
    const float* ch    = (const float*)d_in[5];
    const void*  coll  = d_in[6];
    float* out = (float*)d_out;

    hipLaunchKernelGGL(fused_kernel, dim3(256), dim3(1024), 0, stream,
                       (const f32x4*)fac, (const f32x4*)inh, (const f32x4*)ch, (f32x4*)out,
                       pos, goal, spike, fac, inh, ch, coll, out);
}

// Round 14
// 137.748 us; speedup vs baseline: 1.0178x; 1.0178x over previous
//
#include <hip/hip_runtime.h>

// Problem constants
static constexpr int B_ = 64, A_ = 32, BOARD_ = 64, D_ = 5;
static constexpr long long FACN = (long long)B_ * A_ * BOARD_ * BOARD_ * D_; // 41,943,040 floats
static constexpr long long CHN  = (long long)B_ * A_ * BOARD_ * BOARD_;      //  8,388,608 floats
static constexpr int NAG = B_ * A_;                                          // 2048 agents
static constexpr int SL  = BOARD_ * BOARD_ * D_;                             // 20480 floats / agent fac slab
static constexpr int SLC = BOARD_ * BOARD_;                                  //  4096 floats / agent ch slab

// exp(-1/50), exp(-1/20)
static constexpr float FAC_DECAY = 0.9801986733067553f;
static constexpr float INH_DECAY = 0.9512294245007140f;

typedef float f32x4 __attribute__((ext_vector_type(4)));

// FINAL (r12 reproduction — best measured config, 137.6 us):
// Fused kernel, 512 blocks x 1024 threads (2 blocks/CU, 32 waves/CU max
// occupancy, 4 long sequential DRAM streams per CU). nt loads + nt stores
// (pure streaming; all cache-policy combos measured, nt/nt wins), software
// pipeline (prefetch next 4096-vector group before storing current),
// wave-uniform region pick (FACV, 2*FACV are multiples of 4096),
// chunk-local race-free agent corrections after __syncthreads.
__global__ __launch_bounds__(1024) void fused_kernel(
    const f32x4* __restrict__ fac4, const f32x4* __restrict__ inh4,
    const f32x4* __restrict__ ch4, f32x4* __restrict__ out4,
    const float* __restrict__ pos, const float* __restrict__ goal,
    const float* __restrict__ spike,
    const float* __restrict__ fac_in, const float* __restrict__ inh_in,
    const float* __restrict__ ch_in,
    const void* __restrict__ coll,
    float* __restrict__ out)
{
    const int FACV = (int)(FACN / 4);       // 10,485,760 vectors (= 2560*4096)
    const int C = 45056;                    // vectors per block (= 11*4096); 512*C = total
    const int t = threadIdx.x;
    const int bid = blockIdx.x;
    const int base = bid * C;

    __shared__ int s_w4, s_h2;
    if (t == 0) { s_w4 = 1; s_h2 = 1; }
    __syncthreads();

    // ---- Phase 1: streaming decay (groups of 4096 vectors) ----
    auto ldgrp = [&](int G, f32x4 v[4], float& c) {
        const f32x4* __restrict__ s;
        if (G < FACV)          { s = fac4 + G;             c = FAC_DECAY; }
        else if (G < 2 * FACV) { s = inh4 + (G - FACV);    c = INH_DECAY; }
        else                   { s = ch4 + (G - 2 * FACV); c = 0.9f; }
        v[0] = __builtin_nontemporal_load(&s[t]);
        v[1] = __builtin_nontemporal_load(&s[t + 1024]);
        v[2] = __builtin_nontemporal_load(&s[t + 2048]);
        v[3] = __builtin_nontemporal_load(&s[t + 3072]);
    };

    {
        f32x4 v[4]; float c;
        ldgrp(base, v, c);
        int off = 0;
        while (true) {
            f32x4 w[4]; float c2;
            const int noff = off + 4096;
            if (noff < C) ldgrp(base + noff, w, c2);   // prefetch next group first
            f32x4* __restrict__ d = out4 + base + off;
            __builtin_nontemporal_store(v[0] * c, &d[t]);
            __builtin_nontemporal_store(v[1] * c, &d[t + 1024]);
            __builtin_nontemporal_store(v[2] * c, &d[t + 2048]);
            __builtin_nontemporal_store(v[3] * c, &d[t + 3072]);
            if (noff >= C) break;
            v[0] = w[0]; v[1] = w[1]; v[2] = w[2]; v[3] = w[3]; c = c2;
            off = noff;
        }
    }

    // ---- collisions-dtype sniff (2048 bytes = smallest possible encoding) ----
    {
        const unsigned int* cw = (const unsigned int*)coll;
        if (t < 512) {
            unsigned int w = cw[t];
            if (!(w == 0u || w == 1u || w == 0x3F800000u)) s_w4 = 0;
            unsigned int lo = w & 0xFFFFu, hi = w >> 16;
            if (!((lo == 0u || lo == 1u || lo == 0x3F80u || lo == 0x3C00u) &&
                  (hi == 0u || hi == 1u || hi == 0x3F80u || hi == 0x3C00u)))
                s_h2 = 0;
        }
    }
    __threadfence_block();
    __syncthreads();   // this block's streaming stores ordered; sniff flags ready
    const int f = s_w4 ? 4 : (s_h2 ? 2 : 1);

    // ---- Phase 2: chunk-local agent corrections ----
    const long long CF = (long long)C * 4;  // 180,224 floats per chunk
    const long long F0 = (long long)bid * CF, F1 = F0 + CF;

    auto fix_agent = [&](int ia, int region) {  // region 0=fac, 1=inh, 2=ch
        float px = pos[ia * 2 + 0];
        float py = pos[ia * 2 + 1];
        int x = min(BOARD_ - 1, max(0, (int)px));   // trunc like .astype(int32); pos >= 0
        int y = min(BOARD_ - 1, max(0, (int)py));
        int lcell = y * BOARD_ + x;                 // 0..4095

        bool c;
        if (f == 4)      c = ((const unsigned int*)coll)[ia] != 0u;
        else if (f == 2) c = ((const unsigned short*)coll)[ia] != 0u;
        else             c = ((const unsigned char*)coll)[ia] != 0u;

        float chv = ch_in[(long long)ia * SLC + lcell] * 0.9f + (c ? 0.1f : 0.0f);
        float safety = 1.0f - fminf(fmaxf(chv, 0.0f), 1.0f);

        if (region == 2) {
            long long fl = 2 * FACN + (long long)ia * SLC + lcell;
            if (fl >= F0 && fl < F1) out[fl] = chv;
            return;
        }

        bool safe = safety > 0.7f;
        float gx = goal[ia * 2 + 0] - px;
        float gy = goal[ia * 2 + 1] - py;
        float n = sqrtf(gx * gx + gy * gy) + 1e-8f;
        float gnx = gx / n, gny = gy / n;
        float align[5];
        align[0] = 0.5f;
        align[1] = (gnx + 1.0f) * 0.5f;
        align[2] = (gny + 1.0f) * 0.5f;
        align[3] = (1.0f - gnx) * 0.5f;
        align[4] = (1.0f - gny) * 0.5f;

        long long cdb = (long long)ia * SL + (long long)lcell * D_;  // within-region float base
#pragma unroll
        for (int d = 0; d < D_; ++d) {
            bool sp = spike[ia * D_ + d] > 0.5f;
            long long fl;
            float v;
            if (region == 0) {
                bool fc = sp && safe && (align[d] > 0.6f);
                v = fac_in[cdb + d] * FAC_DECAY + (fc ? 0.0002f : 0.0f);
                fl = cdb + d;
            } else {
                bool ic = sp && (!safe || (align[d] <= 0.4f));
                v = inh_in[cdb + d] * INH_DECAY + (ic ? 0.0001f : 0.0f);
                fl = FACN + cdb + d;
            }
            if (fl >= F0 && fl < F1) out[fl] = v;
        }
    };

    // fac region: chunk may touch up to ceil(180224/20480)+1 = 10 slabs -> 16 threads
    if (t < 16) {
        long long a1 = min(F1, FACN);
        if (F0 < a1) {
            int ia = (int)(F0 / SL) + t;
            int iaMax = (int)((a1 - 1) / SL);
            if (ia <= iaMax && ia < NAG) fix_agent(ia, 0);
        }
    }
    // inh region: same bound -> 16 threads
    else if (t < 32) {
        long long b0 = max(F0, FACN), b1 = min(F1, 2 * FACN);
        if (b0 < b1) {
            int ia = (int)((b0 - FACN) / SL) + (t - 16);
            int iaMax = (int)((b1 - FACN - 1) / SL);
            if (ia <= iaMax && ia < NAG) fix_agent(ia, 1);
        }
    }
    // ch region: up to ceil(180224/4096)+1 = 45 slabs -> 48 threads
    else if (t >= 64 && t < 112) {
        long long c0 = max(F0, 2 * FACN), c1 = min(F1, 2 * FACN + CHN);
        if (c0 < c1) {
            int ia = (int)((c0 - 2 * FACN) / SLC) + (t - 64);
            int iaMax = (int)((c1 - 2 * FACN - 1) / SLC);
            if (ia <= iaMax && ia < NAG) fix_agent(ia, 2);
        }
    }
    // safety: 512 blocks x 4 agents = 2048 (floats past all chunks; one writer each)
    else if (t >= 128 && t < 132) {
        int ia = bid * 4 + (t - 128);
        float px = pos[ia * 2 + 0];
        float py = pos[ia * 2 + 1];
        int x = min(BOARD_ - 1, max(0, (int)px));
        int y = min(BOARD_ - 1, max(0, (int)py));
        int lcell = y * BOARD_ + x;
        bool c;
        if (f == 4)      c = ((const unsigned int*)coll)[ia] != 0u;
        else if (f == 2) c = ((const unsigned short*)coll)[ia] != 0u;
        else             c = ((const unsigned char*)coll)[ia] != 0u;
        float chv = ch_in[(long long)ia * SLC + lcell] * 0.9f + (c ? 0.1f : 0.0f);
        out[2 * FACN + CHN + ia] = 1.0f - fminf(fmaxf(chv, 0.0f), 1.0f);
    }
}

extern "C" void kernel_launch(void* const* d_in, const int* in_sizes, int n_in,
                              void* d_out, int out_size, void* d_ws, size_t ws_size,
                              hipStream_t stream) {
    const float* pos   = (const float*)d_in[0];
    const float* goal  = (const float*)d_in[1];
    const float* spike = (const float*)d_in[2];
    const float* fac   = (const float*)d_in[3];
    const float* inh   = (const float*)d_in[4];
    const float* ch    = (const float*)d_in[5];
    const void*  coll  = d_in[6];
    float* out = (float*)d_out;

    hipLaunchKernelGGL(fused_kernel, dim3(512), dim3(1024), 0, stream,
                       (const f32x4*)fac, (const f32x4*)inh, (const f32x4*)ch, (f32x4*)out,
                       pos, goal, spike, fac, inh, ch, coll, out);
}